// Round 2
// baseline (707.720 us; speedup 1.0000x reference)
//
#include <hip/hip_runtime.h>
#include <hip/hip_bf16.h>
#include <stdint.h>

// GraphNet global block, MI355X. R2: counting-sort nodes by graph, then one
// block per graph does gather -> 3-layer f16-MFMA MLP -> LN -> register
// segment-sum -> fused per-graph MLP epilogue. No fp32 atomics anywhere.

#define NNODES 500000
#define NGRAPHS 4096
#define LDH 136       // padded f16 row stride

typedef __attribute__((ext_vector_type(8))) _Float16 half8;
typedef __attribute__((ext_vector_type(4))) float floatx4;

// ---------------- prep: transpose weights to f16 [N][K] ----------------
__global__ void prep_kernel(const float* __restrict__ w1, const float* __restrict__ w2,
                            const float* __restrict__ w3,
                            _Float16* __restrict__ w1T, _Float16* __restrict__ w2T,
                            _Float16* __restrict__ w3T) {
    int i = blockIdx.x * 256 + threadIdx.x;   // 0..16383
    if (i < 128 * 128) {
        int n = i >> 7, k = i & 127;
        w1T[i] = (_Float16)w1[k * 128 + n];
        w2T[i] = (_Float16)w2[k * 128 + n];
    }
    if (i < 64 * 128) {
        int n = i >> 7, k = i & 127;
        w3T[i] = (_Float16)w3[k * 64 + n];
    }
}

// ---------------- counting sort ----------------
__global__ void hist_kernel(const int* __restrict__ batch, int* __restrict__ cnt) {
    int i = blockIdx.x * 256 + threadIdx.x;
    if (i < NNODES) atomicAdd(&cnt[batch[i]], 1);
}

__global__ void scan_kernel(const int* __restrict__ cnt, int* __restrict__ offs) {
    __shared__ int ssum[256];
    int t = threadIdx.x;
    int base = t * 16;
    int s = 0;
    #pragma unroll
    for (int j = 0; j < 16; ++j) s += cnt[base + j];
    ssum[t] = s;
    __syncthreads();
    for (int d = 1; d < 256; d <<= 1) {
        int v = (t >= d) ? ssum[t - d] : 0;
        __syncthreads();
        ssum[t] += v;
        __syncthreads();
    }
    int run = ssum[t] - s;   // exclusive prefix
    #pragma unroll
    for (int j = 0; j < 16; ++j) { offs[base + j] = run; run += cnt[base + j]; }
    if (t == 255) offs[4096] = run;
}

__global__ void scatter_kernel(const int* __restrict__ batch, const int* __restrict__ offs,
                               int* __restrict__ cursor, int* __restrict__ sorted) {
    int i = blockIdx.x * 256 + threadIdx.x;
    if (i < NNODES) {
        int g = batch[i];
        int p = offs[g] + atomicAdd(&cursor[g], 1);
        sorted[p] = i;
    }
}

// ---------------- fused: per-graph node MLP + segment sum + graph MLP --------
__global__ __launch_bounds__(256, 4) void node_fused(
    const float* __restrict__ x, const float* __restrict__ u,
    const int* __restrict__ sorted, const int* __restrict__ offs,
    const _Float16* __restrict__ w1T, const _Float16* __restrict__ w2T,
    const _Float16* __restrict__ w3T,
    const float* __restrict__ b1, const float* __restrict__ b2, const float* __restrict__ b3,
    const float* __restrict__ lng, const float* __restrict__ lnb,
    const float* __restrict__ w4, const float* __restrict__ b4,
    const float* __restrict__ w5, const float* __restrict__ b5,
    const float* __restrict__ w6, const float* __restrict__ b6,
    const float* __restrict__ g2, const float* __restrict__ bb2,
    float* __restrict__ out)
{
    __shared__ __align__(16) _Float16 hA[128 * LDH];   // 34.8 KB
    __shared__ int sIdx[128];
    __shared__ float uf[64];
    __shared__ float ub[128];          // layer-1 effective bias (b1 + u @ W1[64:,:])
    __shared__ float waveacc[4][64];
    __shared__ float zf[128], h1[128], pbuf[2][128];

    const int g = blockIdx.x;
    const int tid = threadIdx.x;
    const int wave = tid >> 6;
    const int lane = tid & 63;
    const int q = lane >> 4;
    const int l16 = lane & 15;
    const int beg = offs[g];
    const int cnt = offs[g + 1] - beg;

    if (tid < 64) uf[tid] = u[(size_t)g * 64 + tid];
    __syncthreads();
    if (tid < 128) {
        float s = b1[tid];
        const _Float16* wp = w1T + tid * 128 + 64;
        #pragma unroll
        for (int k = 0; k < 64; ++k) s += uf[k] * (float)wp[k];
        ub[tid] = s;
    }

    float regacc[4] = {0.f, 0.f, 0.f, 0.f};
    const int ntiles = (cnt + 127) >> 7;
    const int rowg = (wave >> 1) * 64;
    const int colg = (wave & 1) * 64;
    const int rowg3 = wave * 32;

    for (int t = 0; t < ntiles; ++t) {
        if (tid < 128) {
            int rr = t * 128 + tid;
            sIdx[tid] = (rr < cnt) ? sorted[beg + rr] : -1;
        }
        __syncthreads();
        // stage x rows (cols 0..63) as f16
        for (int i = tid; i < 128 * 16; i += 256) {
            int r = i >> 4, c4 = (i & 15) << 2;
            int idx = sIdx[r];
            float4 v = make_float4(0.f, 0.f, 0.f, 0.f);
            if (idx >= 0) v = *(const float4*)(x + (size_t)idx * 64 + c4);
            _Float16* p = &hA[r * LDH + c4];
            p[0] = (_Float16)v.x; p[1] = (_Float16)v.y;
            p[2] = (_Float16)v.z; p[3] = (_Float16)v.w;
        }
        __syncthreads();

        // ---- layer 1: 128x128, K=64 (u folded into bias) ----
        {
            floatx4 acc[4][4];
            #pragma unroll
            for (int ct = 0; ct < 4; ++ct) {
                float bv = ub[colg + ct * 16 + l16];
                #pragma unroll
                for (int rt = 0; rt < 4; ++rt) acc[rt][ct] = (floatx4){bv, bv, bv, bv};
            }
            half8 bfr[2][4];
            #pragma unroll
            for (int ks = 0; ks < 2; ++ks)
                #pragma unroll
                for (int ct = 0; ct < 4; ++ct)
                    bfr[ks][ct] = *(const half8*)(w1T + (colg + ct * 16 + l16) * 128 + ks * 32 + q * 8);
            #pragma unroll
            for (int ks = 0; ks < 2; ++ks) {
                half8 af[4];
                #pragma unroll
                for (int rt = 0; rt < 4; ++rt)
                    af[rt] = *(const half8*)(&hA[(rowg + rt * 16 + l16) * LDH + ks * 32 + q * 8]);
                #pragma unroll
                for (int rt = 0; rt < 4; ++rt)
                    #pragma unroll
                    for (int ct = 0; ct < 4; ++ct)
                        acc[rt][ct] = __builtin_amdgcn_mfma_f32_16x16x32_f16(
                            af[rt], bfr[ks][ct], acc[rt][ct], 0, 0, 0);
            }
            __syncthreads();
            #pragma unroll
            for (int rt = 0; rt < 4; ++rt)
                #pragma unroll
                for (int ct = 0; ct < 4; ++ct)
                    #pragma unroll
                    for (int j = 0; j < 4; ++j) {
                        float v = acc[rt][ct][j];
                        v = v > 0.f ? v : 0.f;
                        hA[(rowg + rt * 16 + q * 4 + j) * LDH + colg + ct * 16 + l16] = (_Float16)v;
                    }
            __syncthreads();
        }

        // ---- layer 2: 128x128, K=128, in-place ----
        {
            floatx4 acc[4][4];
            #pragma unroll
            for (int ct = 0; ct < 4; ++ct) {
                float bv = b2[colg + ct * 16 + l16];
                #pragma unroll
                for (int rt = 0; rt < 4; ++rt) acc[rt][ct] = (floatx4){bv, bv, bv, bv};
            }
            half8 bfr[4][4];
            #pragma unroll
            for (int ks = 0; ks < 4; ++ks)
                #pragma unroll
                for (int ct = 0; ct < 4; ++ct)
                    bfr[ks][ct] = *(const half8*)(w2T + (colg + ct * 16 + l16) * 128 + ks * 32 + q * 8);
            #pragma unroll
            for (int ks = 0; ks < 4; ++ks) {
                half8 af[4];
                #pragma unroll
                for (int rt = 0; rt < 4; ++rt)
                    af[rt] = *(const half8*)(&hA[(rowg + rt * 16 + l16) * LDH + ks * 32 + q * 8]);
                #pragma unroll
                for (int rt = 0; rt < 4; ++rt)
                    #pragma unroll
                    for (int ct = 0; ct < 4; ++ct)
                        acc[rt][ct] = __builtin_amdgcn_mfma_f32_16x16x32_f16(
                            af[rt], bfr[ks][ct], acc[rt][ct], 0, 0, 0);
            }
            __syncthreads();
            #pragma unroll
            for (int rt = 0; rt < 4; ++rt)
                #pragma unroll
                for (int ct = 0; ct < 4; ++ct)
                    #pragma unroll
                    for (int j = 0; j < 4; ++j) {
                        float v = acc[rt][ct][j];
                        v = v > 0.f ? v : 0.f;
                        hA[(rowg + rt * 16 + q * 4 + j) * LDH + colg + ct * 16 + l16] = (_Float16)v;
                    }
            __syncthreads();
        }

        // ---- layer 3: 128x64 + LN + register segment-sum ----
        {
            floatx4 acc[2][4];
            #pragma unroll
            for (int ct = 0; ct < 4; ++ct) {
                float bv = b3[ct * 16 + l16];
                acc[0][ct] = (floatx4){bv, bv, bv, bv};
                acc[1][ct] = (floatx4){bv, bv, bv, bv};
            }
            half8 bfr[4][4];
            #pragma unroll
            for (int ks = 0; ks < 4; ++ks)
                #pragma unroll
                for (int ct = 0; ct < 4; ++ct)
                    bfr[ks][ct] = *(const half8*)(w3T + (ct * 16 + l16) * 128 + ks * 32 + q * 8);
            #pragma unroll
            for (int ks = 0; ks < 4; ++ks) {
                half8 af[2];
                #pragma unroll
                for (int rt = 0; rt < 2; ++rt)
                    af[rt] = *(const half8*)(&hA[(rowg3 + rt * 16 + l16) * LDH + ks * 32 + q * 8]);
                #pragma unroll
                for (int rt = 0; rt < 2; ++rt)
                    #pragma unroll
                    for (int ct = 0; ct < 4; ++ct)
                        acc[rt][ct] = __builtin_amdgcn_mfma_f32_16x16x32_f16(
                            af[rt], bfr[ks][ct], acc[rt][ct], 0, 0, 0);
            }
            float gct[4], bct[4];
            #pragma unroll
            for (int ct = 0; ct < 4; ++ct) {
                gct[ct] = lng[ct * 16 + l16];
                bct[ct] = lnb[ct * 16 + l16];
            }
            #pragma unroll
            for (int rt = 0; rt < 2; ++rt)
                #pragma unroll
                for (int j = 0; j < 4; ++j) {
                    int rloc = rowg3 + rt * 16 + q * 4 + j;
                    float v0 = acc[rt][0][j], v1 = acc[rt][1][j];
                    float v2 = acc[rt][2][j], v3 = acc[rt][3][j];
                    float s = v0 + v1 + v2 + v3;
                    float ss = v0 * v0 + v1 * v1 + v2 * v2 + v3 * v3;
                    #pragma unroll
                    for (int m = 1; m < 16; m <<= 1) {
                        s += __shfl_xor(s, m, 16);
                        ss += __shfl_xor(ss, m, 16);
                    }
                    float mean = s * (1.f / 64.f);
                    float var = ss * (1.f / 64.f) - mean * mean;
                    float rstd = rsqrtf(var + 1e-5f);
                    if (t * 128 + rloc < cnt) {
                        regacc[0] += (v0 - mean) * rstd * gct[0] + bct[0];
                        regacc[1] += (v1 - mean) * rstd * gct[1] + bct[1];
                        regacc[2] += (v2 - mean) * rstd * gct[2] + bct[2];
                        regacc[3] += (v3 - mean) * rstd * gct[3] + bct[3];
                    }
                }
            __syncthreads();   // hA free for next tile
        }
    }

    // ---- reduce segment sum: lanes (q) then waves ----
    #pragma unroll
    for (int ct = 0; ct < 4; ++ct) {
        float v = regacc[ct];
        v += __shfl_xor(v, 16, 64);
        v += __shfl_xor(v, 32, 64);
        if (lane < 16) waveacc[wave][ct * 16 + lane] = v;
    }
    __syncthreads();
    if (tid < 64) {
        float a = waveacc[0][tid] + waveacc[1][tid] + waveacc[2][tid] + waveacc[3][tid];
        zf[tid] = a;            // agg
        zf[64 + tid] = uf[tid]; // concat u
    }
    __syncthreads();

    // ---- fused per-graph MLP (phase 2), split-k fp32 ----
    {   // layer 4
        int n = tid & 127, half = tid >> 7;
        float s = half ? 0.f : b4[n];
        #pragma unroll 16
        for (int k = 0; k < 64; ++k) s = fmaf(zf[half * 64 + k], w4[(half * 64 + k) * 128 + n], s);
        pbuf[half][n] = s;
    }
    __syncthreads();
    if (tid < 128) h1[tid] = fmaxf(pbuf[0][tid] + pbuf[1][tid], 0.f);
    __syncthreads();
    {   // layer 5
        int n = tid & 127, half = tid >> 7;
        float s = half ? 0.f : b5[n];
        #pragma unroll 16
        for (int k = 0; k < 64; ++k) s = fmaf(h1[half * 64 + k], w5[(half * 64 + k) * 128 + n], s);
        pbuf[half][n] = s;
    }
    __syncthreads();
    if (tid < 128) zf[tid] = fmaxf(pbuf[0][tid] + pbuf[1][tid], 0.f);
    __syncthreads();
    if (tid < 128) {   // layer 6: 64 outputs, 2-way split-k
        int n = tid & 63, half = (tid >> 6) & 1;
        float s = half ? 0.f : b6[n];
        #pragma unroll 16
        for (int k = 0; k < 64; ++k) s = fmaf(zf[half * 64 + k], w6[(half * 64 + k) * 64 + n], s);
        pbuf[half][n] = s;
    }
    __syncthreads();
    if (tid < 64) {
        float s = pbuf[0][tid] + pbuf[1][tid];
        float sum = s, ssq = s * s;
        #pragma unroll
        for (int m = 1; m < 64; m <<= 1) {
            sum += __shfl_xor(sum, m, 64);
            ssq += __shfl_xor(ssq, m, 64);
        }
        float mean = sum * (1.f / 64.f);
        float var = ssq * (1.f / 64.f) - mean * mean;
        float rstd = rsqrtf(var + 1e-5f);
        out[(size_t)g * 64 + tid] = (s - mean) * rstd * g2[tid] + bb2[tid] + uf[tid];
    }
}

extern "C" void kernel_launch(void* const* d_in, const int* in_sizes, int n_in,
                              void* d_out, int out_size, void* d_ws, size_t ws_size,
                              hipStream_t stream) {
    const float* x   = (const float*)d_in[0];
    const float* u   = (const float*)d_in[1];
    const int*   bt  = (const int*)d_in[2];
    const float* w1  = (const float*)d_in[3];
    const float* b1  = (const float*)d_in[4];
    const float* w2  = (const float*)d_in[5];
    const float* b2  = (const float*)d_in[6];
    const float* w3  = (const float*)d_in[7];
    const float* b3  = (const float*)d_in[8];
    const float* lng = (const float*)d_in[9];
    const float* lnb = (const float*)d_in[10];
    const float* w4  = (const float*)d_in[11];
    const float* b4  = (const float*)d_in[12];
    const float* w5  = (const float*)d_in[13];
    const float* b5  = (const float*)d_in[14];
    const float* w6  = (const float*)d_in[15];
    const float* b6  = (const float*)d_in[16];
    const float* g2  = (const float*)d_in[17];
    const float* bb2 = (const float*)d_in[18];
    float* out = (float*)d_out;

    char* p = (char*)d_ws;
    _Float16* w1T   = (_Float16*)p;            p += 128 * 128 * 2;
    _Float16* w2T   = (_Float16*)p;            p += 128 * 128 * 2;
    _Float16* w3T   = (_Float16*)p;            p += 64 * 128 * 2;
    int* cnt        = (int*)p;                 p += 4096 * 4;
    int* cursor     = (int*)p;                 p += 4096 * 4;
    int* offs       = (int*)p;                 p += 4100 * 4;
    int* sorted     = (int*)p;                 p += NNODES * 4;

    hipMemsetAsync(cnt, 0, 2 * 4096 * sizeof(int), stream);   // cnt + cursor
    prep_kernel<<<64, 256, 0, stream>>>(w1, w2, w3, w1T, w2T, w3T);
    hist_kernel<<<(NNODES + 255) / 256, 256, 0, stream>>>(bt, cnt);
    scan_kernel<<<1, 256, 0, stream>>>(cnt, offs);
    scatter_kernel<<<(NNODES + 255) / 256, 256, 0, stream>>>(bt, offs, cursor, sorted);
    node_fused<<<NGRAPHS, 256, 0, stream>>>(
        x, u, sorted, offs, w1T, w2T, w3T, b1, b2, b3, lng, lnb,
        w4, b4, w5, b5, w6, b6, g2, bb2, out);
}

// Round 3
// 571.045 us; speedup vs baseline: 1.2393x; 1.2393x over previous
//
#include <hip/hip_runtime.h>
#include <hip/hip_bf16.h>
#include <stdint.h>

// GraphNet global block, MI355X. R3: counting-sort nodes by graph, then one
// block per graph: gather -> 3-layer f16-MFMA MLP -> LN -> register
// segment-sum -> fused per-graph MLP epilogue. No fp32 atomics.
// R3 fix vs R2: launch_bounds (256,2) (R2's (256,4) forced ~850MB of scratch
// spill traffic), B-fragments loaded per-ks in K=128 layers to cut reg demand.

#define NNODES 500000
#define NGRAPHS 4096
#define LDH 136       // padded f16 row stride

typedef __attribute__((ext_vector_type(8))) _Float16 half8;
typedef __attribute__((ext_vector_type(4))) float floatx4;

// ---------------- prep: transpose weights to f16 [N][K] ----------------
__global__ void prep_kernel(const float* __restrict__ w1, const float* __restrict__ w2,
                            const float* __restrict__ w3,
                            _Float16* __restrict__ w1T, _Float16* __restrict__ w2T,
                            _Float16* __restrict__ w3T) {
    int i = blockIdx.x * 256 + threadIdx.x;   // 0..16383
    if (i < 128 * 128) {
        int n = i >> 7, k = i & 127;
        w1T[i] = (_Float16)w1[k * 128 + n];
        w2T[i] = (_Float16)w2[k * 128 + n];
    }
    if (i < 64 * 128) {
        int n = i >> 7, k = i & 127;
        w3T[i] = (_Float16)w3[k * 64 + n];
    }
}

// ---------------- counting sort ----------------
__global__ void hist_kernel(const int* __restrict__ batch, int* __restrict__ cnt) {
    int i = blockIdx.x * 256 + threadIdx.x;
    if (i < NNODES) atomicAdd(&cnt[batch[i]], 1);
}

__global__ void scan_kernel(const int* __restrict__ cnt, int* __restrict__ offs) {
    __shared__ int ssum[256];
    int t = threadIdx.x;
    int base = t * 16;
    int s = 0;
    #pragma unroll
    for (int j = 0; j < 16; ++j) s += cnt[base + j];
    ssum[t] = s;
    __syncthreads();
    for (int d = 1; d < 256; d <<= 1) {
        int v = (t >= d) ? ssum[t - d] : 0;
        __syncthreads();
        ssum[t] += v;
        __syncthreads();
    }
    int run = ssum[t] - s;   // exclusive prefix
    #pragma unroll
    for (int j = 0; j < 16; ++j) { offs[base + j] = run; run += cnt[base + j]; }
    if (t == 255) offs[4096] = run;
}

__global__ void scatter_kernel(const int* __restrict__ batch, const int* __restrict__ offs,
                               int* __restrict__ cursor, int* __restrict__ sorted) {
    int i = blockIdx.x * 256 + threadIdx.x;
    if (i < NNODES) {
        int g = batch[i];
        int p = offs[g] + atomicAdd(&cursor[g], 1);
        sorted[p] = i;
    }
}

// ---------------- fused: per-graph node MLP + segment sum + graph MLP --------
__global__ __launch_bounds__(256, 2) void node_fused(
    const float* __restrict__ x, const float* __restrict__ u,
    const int* __restrict__ sorted, const int* __restrict__ offs,
    const _Float16* __restrict__ w1T, const _Float16* __restrict__ w2T,
    const _Float16* __restrict__ w3T,
    const float* __restrict__ b1, const float* __restrict__ b2, const float* __restrict__ b3,
    const float* __restrict__ lng, const float* __restrict__ lnb,
    const float* __restrict__ w4, const float* __restrict__ b4,
    const float* __restrict__ w5, const float* __restrict__ b5,
    const float* __restrict__ w6, const float* __restrict__ b6,
    const float* __restrict__ g2, const float* __restrict__ bb2,
    float* __restrict__ out)
{
    __shared__ __align__(16) _Float16 hA[128 * LDH];   // 34.8 KB
    __shared__ int sIdx[128];
    __shared__ float uf[64];
    __shared__ float ub[128];          // layer-1 effective bias (b1 + u @ W1[64:,:])
    __shared__ float waveacc[4][64];
    __shared__ float zf[128], h1[128], pbuf[2][128];

    const int g = blockIdx.x;
    const int tid = threadIdx.x;
    const int wave = tid >> 6;
    const int lane = tid & 63;
    const int q = lane >> 4;
    const int l16 = lane & 15;
    const int beg = offs[g];
    const int cnt = offs[g + 1] - beg;

    if (tid < 64) uf[tid] = u[(size_t)g * 64 + tid];
    __syncthreads();
    if (tid < 128) {
        float s = b1[tid];
        const _Float16* wp = w1T + tid * 128 + 64;
        #pragma unroll
        for (int k = 0; k < 64; ++k) s += uf[k] * (float)wp[k];
        ub[tid] = s;
    }

    float regacc[4] = {0.f, 0.f, 0.f, 0.f};
    const int ntiles = (cnt + 127) >> 7;
    const int rowg = (wave >> 1) * 64;
    const int colg = (wave & 1) * 64;
    const int rowg3 = wave * 32;

    for (int t = 0; t < ntiles; ++t) {
        if (tid < 128) {
            int rr = t * 128 + tid;
            sIdx[tid] = (rr < cnt) ? sorted[beg + rr] : -1;
        }
        __syncthreads();
        // stage x rows (cols 0..63) as f16
        for (int i = tid; i < 128 * 16; i += 256) {
            int r = i >> 4, c4 = (i & 15) << 2;
            int idx = sIdx[r];
            float4 v = make_float4(0.f, 0.f, 0.f, 0.f);
            if (idx >= 0) v = *(const float4*)(x + (size_t)idx * 64 + c4);
            _Float16* p = &hA[r * LDH + c4];
            p[0] = (_Float16)v.x; p[1] = (_Float16)v.y;
            p[2] = (_Float16)v.z; p[3] = (_Float16)v.w;
        }
        __syncthreads();

        // ---- layer 1: 128x128, K=64 (u folded into bias) ----
        {
            floatx4 acc[4][4];
            #pragma unroll
            for (int ct = 0; ct < 4; ++ct) {
                float bv = ub[colg + ct * 16 + l16];
                #pragma unroll
                for (int rt = 0; rt < 4; ++rt) acc[rt][ct] = (floatx4){bv, bv, bv, bv};
            }
            #pragma unroll
            for (int ks = 0; ks < 2; ++ks) {
                half8 bfr[4];
                #pragma unroll
                for (int ct = 0; ct < 4; ++ct)
                    bfr[ct] = *(const half8*)(w1T + (colg + ct * 16 + l16) * 128 + ks * 32 + q * 8);
                half8 af[4];
                #pragma unroll
                for (int rt = 0; rt < 4; ++rt)
                    af[rt] = *(const half8*)(&hA[(rowg + rt * 16 + l16) * LDH + ks * 32 + q * 8]);
                #pragma unroll
                for (int rt = 0; rt < 4; ++rt)
                    #pragma unroll
                    for (int ct = 0; ct < 4; ++ct)
                        acc[rt][ct] = __builtin_amdgcn_mfma_f32_16x16x32_f16(
                            af[rt], bfr[ct], acc[rt][ct], 0, 0, 0);
            }
            __syncthreads();
            #pragma unroll
            for (int rt = 0; rt < 4; ++rt)
                #pragma unroll
                for (int ct = 0; ct < 4; ++ct)
                    #pragma unroll
                    for (int j = 0; j < 4; ++j) {
                        float v = acc[rt][ct][j];
                        v = v > 0.f ? v : 0.f;
                        hA[(rowg + rt * 16 + q * 4 + j) * LDH + colg + ct * 16 + l16] = (_Float16)v;
                    }
            __syncthreads();
        }

        // ---- layer 2: 128x128, K=128, in-place ----
        {
            floatx4 acc[4][4];
            #pragma unroll
            for (int ct = 0; ct < 4; ++ct) {
                float bv = b2[colg + ct * 16 + l16];
                #pragma unroll
                for (int rt = 0; rt < 4; ++rt) acc[rt][ct] = (floatx4){bv, bv, bv, bv};
            }
            #pragma unroll
            for (int ks = 0; ks < 4; ++ks) {
                half8 bfr[4];
                #pragma unroll
                for (int ct = 0; ct < 4; ++ct)
                    bfr[ct] = *(const half8*)(w2T + (colg + ct * 16 + l16) * 128 + ks * 32 + q * 8);
                half8 af[4];
                #pragma unroll
                for (int rt = 0; rt < 4; ++rt)
                    af[rt] = *(const half8*)(&hA[(rowg + rt * 16 + l16) * LDH + ks * 32 + q * 8]);
                #pragma unroll
                for (int rt = 0; rt < 4; ++rt)
                    #pragma unroll
                    for (int ct = 0; ct < 4; ++ct)
                        acc[rt][ct] = __builtin_amdgcn_mfma_f32_16x16x32_f16(
                            af[rt], bfr[ct], acc[rt][ct], 0, 0, 0);
            }
            __syncthreads();
            #pragma unroll
            for (int rt = 0; rt < 4; ++rt)
                #pragma unroll
                for (int ct = 0; ct < 4; ++ct)
                    #pragma unroll
                    for (int j = 0; j < 4; ++j) {
                        float v = acc[rt][ct][j];
                        v = v > 0.f ? v : 0.f;
                        hA[(rowg + rt * 16 + q * 4 + j) * LDH + colg + ct * 16 + l16] = (_Float16)v;
                    }
            __syncthreads();
        }

        // ---- layer 3: 128x64 + LN + register segment-sum ----
        {
            floatx4 acc[2][4];
            #pragma unroll
            for (int ct = 0; ct < 4; ++ct) {
                float bv = b3[ct * 16 + l16];
                acc[0][ct] = (floatx4){bv, bv, bv, bv};
                acc[1][ct] = (floatx4){bv, bv, bv, bv};
            }
            #pragma unroll
            for (int ks = 0; ks < 4; ++ks) {
                half8 bfr[4];
                #pragma unroll
                for (int ct = 0; ct < 4; ++ct)
                    bfr[ct] = *(const half8*)(w3T + (ct * 16 + l16) * 128 + ks * 32 + q * 8);
                half8 af[2];
                #pragma unroll
                for (int rt = 0; rt < 2; ++rt)
                    af[rt] = *(const half8*)(&hA[(rowg3 + rt * 16 + l16) * LDH + ks * 32 + q * 8]);
                #pragma unroll
                for (int rt = 0; rt < 2; ++rt)
                    #pragma unroll
                    for (int ct = 0; ct < 4; ++ct)
                        acc[rt][ct] = __builtin_amdgcn_mfma_f32_16x16x32_f16(
                            af[rt], bfr[ct], acc[rt][ct], 0, 0, 0);
            }
            float gct[4], bct[4];
            #pragma unroll
            for (int ct = 0; ct < 4; ++ct) {
                gct[ct] = lng[ct * 16 + l16];
                bct[ct] = lnb[ct * 16 + l16];
            }
            #pragma unroll
            for (int rt = 0; rt < 2; ++rt)
                #pragma unroll
                for (int j = 0; j < 4; ++j) {
                    int rloc = rowg3 + rt * 16 + q * 4 + j;
                    float v0 = acc[rt][0][j], v1 = acc[rt][1][j];
                    float v2 = acc[rt][2][j], v3 = acc[rt][3][j];
                    float s = v0 + v1 + v2 + v3;
                    float ss = v0 * v0 + v1 * v1 + v2 * v2 + v3 * v3;
                    #pragma unroll
                    for (int m = 1; m < 16; m <<= 1) {
                        s += __shfl_xor(s, m, 16);
                        ss += __shfl_xor(ss, m, 16);
                    }
                    float mean = s * (1.f / 64.f);
                    float var = ss * (1.f / 64.f) - mean * mean;
                    float rstd = rsqrtf(var + 1e-5f);
                    if (t * 128 + rloc < cnt) {
                        regacc[0] += (v0 - mean) * rstd * gct[0] + bct[0];
                        regacc[1] += (v1 - mean) * rstd * gct[1] + bct[1];
                        regacc[2] += (v2 - mean) * rstd * gct[2] + bct[2];
                        regacc[3] += (v3 - mean) * rstd * gct[3] + bct[3];
                    }
                }
            __syncthreads();   // hA free for next tile
        }
    }

    // ---- reduce segment sum: lanes (q) then waves ----
    #pragma unroll
    for (int ct = 0; ct < 4; ++ct) {
        float v = regacc[ct];
        v += __shfl_xor(v, 16, 64);
        v += __shfl_xor(v, 32, 64);
        if (lane < 16) waveacc[wave][ct * 16 + lane] = v;
    }
    __syncthreads();
    if (tid < 64) {
        float a = waveacc[0][tid] + waveacc[1][tid] + waveacc[2][tid] + waveacc[3][tid];
        zf[tid] = a;            // agg
        zf[64 + tid] = uf[tid]; // concat u
    }
    __syncthreads();

    // ---- fused per-graph MLP (phase 2), split-k fp32 ----
    {   // layer 4
        int n = tid & 127, half = tid >> 7;
        float s = half ? 0.f : b4[n];
        #pragma unroll 16
        for (int k = 0; k < 64; ++k) s = fmaf(zf[half * 64 + k], w4[(half * 64 + k) * 128 + n], s);
        pbuf[half][n] = s;
    }
    __syncthreads();
    if (tid < 128) h1[tid] = fmaxf(pbuf[0][tid] + pbuf[1][tid], 0.f);
    __syncthreads();
    {   // layer 5
        int n = tid & 127, half = tid >> 7;
        float s = half ? 0.f : b5[n];
        #pragma unroll 16
        for (int k = 0; k < 64; ++k) s = fmaf(h1[half * 64 + k], w5[(half * 64 + k) * 128 + n], s);
        pbuf[half][n] = s;
    }
    __syncthreads();
    if (tid < 128) zf[tid] = fmaxf(pbuf[0][tid] + pbuf[1][tid], 0.f);
    __syncthreads();
    if (tid < 128) {   // layer 6: 64 outputs, 2-way split-k
        int n = tid & 63, half = (tid >> 6) & 1;
        float s = half ? 0.f : b6[n];
        #pragma unroll 16
        for (int k = 0; k < 64; ++k) s = fmaf(zf[half * 64 + k], w6[(half * 64 + k) * 64 + n], s);
        pbuf[half][n] = s;
    }
    __syncthreads();
    if (tid < 64) {
        float s = pbuf[0][tid] + pbuf[1][tid];
        float sum = s, ssq = s * s;
        #pragma unroll
        for (int m = 1; m < 64; m <<= 1) {
            sum += __shfl_xor(sum, m, 64);
            ssq += __shfl_xor(ssq, m, 64);
        }
        float mean = sum * (1.f / 64.f);
        float var = ssq * (1.f / 64.f) - mean * mean;
        float rstd = rsqrtf(var + 1e-5f);
        out[(size_t)g * 64 + tid] = (s - mean) * rstd * g2[tid] + bb2[tid] + uf[tid];
    }
}

extern "C" void kernel_launch(void* const* d_in, const int* in_sizes, int n_in,
                              void* d_out, int out_size, void* d_ws, size_t ws_size,
                              hipStream_t stream) {
    const float* x   = (const float*)d_in[0];
    const float* u   = (const float*)d_in[1];
    const int*   bt  = (const int*)d_in[2];
    const float* w1  = (const float*)d_in[3];
    const float* b1  = (const float*)d_in[4];
    const float* w2  = (const float*)d_in[5];
    const float* b2  = (const float*)d_in[6];
    const float* w3  = (const float*)d_in[7];
    const float* b3  = (const float*)d_in[8];
    const float* lng = (const float*)d_in[9];
    const float* lnb = (const float*)d_in[10];
    const float* w4  = (const float*)d_in[11];
    const float* b4  = (const float*)d_in[12];
    const float* w5  = (const float*)d_in[13];
    const float* b5  = (const float*)d_in[14];
    const float* w6  = (const float*)d_in[15];
    const float* b6  = (const float*)d_in[16];
    const float* g2  = (const float*)d_in[17];
    const float* bb2 = (const float*)d_in[18];
    float* out = (float*)d_out;

    char* p = (char*)d_ws;
    _Float16* w1T   = (_Float16*)p;            p += 128 * 128 * 2;
    _Float16* w2T   = (_Float16*)p;            p += 128 * 128 * 2;
    _Float16* w3T   = (_Float16*)p;            p += 64 * 128 * 2;
    int* cnt        = (int*)p;                 p += 4096 * 4;
    int* cursor     = (int*)p;                 p += 4096 * 4;
    int* offs       = (int*)p;                 p += 4100 * 4;
    int* sorted     = (int*)p;                 p += NNODES * 4;

    hipMemsetAsync(cnt, 0, 2 * 4096 * sizeof(int), stream);   // cnt + cursor
    prep_kernel<<<64, 256, 0, stream>>>(w1, w2, w3, w1T, w2T, w3T);
    hist_kernel<<<(NNODES + 255) / 256, 256, 0, stream>>>(bt, cnt);
    scan_kernel<<<1, 256, 0, stream>>>(cnt, offs);
    scatter_kernel<<<(NNODES + 255) / 256, 256, 0, stream>>>(bt, offs, cursor, sorted);
    node_fused<<<NGRAPHS, 256, 0, stream>>>(
        x, u, sorted, offs, w1T, w2T, w3T, b1, b2, b3, lng, lnb,
        w4, b4, w5, b5, w6, b6, g2, bb2, out);
}

// Round 4
// 428.886 us; speedup vs baseline: 1.6501x; 1.3315x over previous
//
#include <hip/hip_runtime.h>
#include <hip/hip_bf16.h>
#include <stdint.h>

// GraphNet global block, MI355X. R4: counting-sort nodes by graph; flat
// 128-row-tile MFMA node kernel (R1 structure, balanced, no spill) over the
// sorted order; epilogue does LDS run-length segment-reduce (~1.9 atomic
// flushes/thread vs 32M in R1). Phase 2 = separate small MFMA kernel.

#define NNODES 500000
#define NGRAPHS 4096
#define ROWS 128
#define LDH 136       // padded f16 row stride
#define LDF 66        // padded f32 row stride for LN-output reuse of hA

typedef __attribute__((ext_vector_type(8))) _Float16 half8;
typedef __attribute__((ext_vector_type(4))) float floatx4;

// ------------- prep: transpose all 6 weights to f16 [N][K] -------------
__global__ void prep_kernel(const float* __restrict__ w1, const float* __restrict__ w2,
                            const float* __restrict__ w3,
                            const float* __restrict__ w4, const float* __restrict__ w5,
                            const float* __restrict__ w6,
                            _Float16* __restrict__ w1T, _Float16* __restrict__ w2T,
                            _Float16* __restrict__ w3T,
                            _Float16* __restrict__ w4T, _Float16* __restrict__ w5T,
                            _Float16* __restrict__ w6T) {
    int i = blockIdx.x * 256 + threadIdx.x;   // 0..32767
    if (i < 128 * 128) {
        int n = i >> 7, k = i & 127;
        w1T[i] = (_Float16)w1[k * 128 + n];
        w2T[i] = (_Float16)w2[k * 128 + n];
        w4T[i] = (_Float16)w4[k * 128 + n];
        w5T[i] = (_Float16)w5[k * 128 + n];
    }
    if (i < 64 * 128) {
        int n = i >> 7, k = i & 127;
        w3T[i] = (_Float16)w3[k * 64 + n];
        w6T[i] = (_Float16)w6[k * 64 + n];
    }
}

// ---------------- counting sort ----------------
__global__ void hist_kernel(const int* __restrict__ batch, int* __restrict__ cnt) {
    int i = blockIdx.x * 256 + threadIdx.x;
    if (i < NNODES) atomicAdd(&cnt[batch[i]], 1);
}

__global__ void scan_kernel(const int* __restrict__ cnt, int* __restrict__ offs) {
    __shared__ int ssum[256];
    int t = threadIdx.x;
    int base = t * 16;
    int s = 0;
    #pragma unroll
    for (int j = 0; j < 16; ++j) s += cnt[base + j];
    ssum[t] = s;
    __syncthreads();
    for (int d = 1; d < 256; d <<= 1) {
        int v = (t >= d) ? ssum[t - d] : 0;
        __syncthreads();
        ssum[t] += v;
        __syncthreads();
    }
    int run = ssum[t] - s;   // exclusive prefix
    #pragma unroll
    for (int j = 0; j < 16; ++j) { offs[base + j] = run; run += cnt[base + j]; }
    if (t == 255) offs[4096] = run;
}

__global__ void scatter_kernel(const int* __restrict__ batch, const int* __restrict__ offs,
                               int* __restrict__ cursor, int* __restrict__ sorted,
                               int* __restrict__ sortedG) {
    int i = blockIdx.x * 256 + threadIdx.x;
    if (i < NNODES) {
        int g = batch[i];
        int p = offs[g] + atomicAdd(&cursor[g], 1);
        sorted[p] = i;
        sortedG[p] = g;
    }
}

// -------- phase 1: flat-tiled node MLP + LN + segment-reduce + few atomics ---
__global__ __launch_bounds__(256, 2) void node_kernel(
    const float* __restrict__ x, const float* __restrict__ u,
    const int* __restrict__ sorted, const int* __restrict__ sortedG,
    const _Float16* __restrict__ w1T, const _Float16* __restrict__ w2T,
    const _Float16* __restrict__ w3T,
    const float* __restrict__ b1, const float* __restrict__ b2, const float* __restrict__ b3,
    const float* __restrict__ lng, const float* __restrict__ lnb,
    float* __restrict__ agg)
{
    __shared__ __align__(16) _Float16 hA[ROWS * LDH];   // 34.8 KB, reused as fp32 LN out
    __shared__ int sIdx[ROWS];
    __shared__ int sG[ROWS];

    float* hF = (float*)hA;   // fp32 view, stride LDF

    const int tid = threadIdx.x;
    const int rowbase = blockIdx.x * ROWS;
    const int wave = tid >> 6;
    const int lane = tid & 63;
    const int q = lane >> 4;
    const int l16 = lane & 15;

    // stage sorted indices + graph ids
    if (tid < ROWS) {
        int gr = rowbase + tid;
        if (gr < NNODES) { sIdx[tid] = sorted[gr]; sG[tid] = sortedG[gr]; }
        else             { sIdx[tid] = -1;         sG[tid] = -1; }
    }
    __syncthreads();

    // stage h0 = concat(x[idx], u[g]) as f16
    for (int i = tid; i < ROWS * 16; i += 256) {
        int r = i >> 4, c4 = (i & 15) << 2;
        int idx = sIdx[r];
        float4 vx = make_float4(0.f, 0.f, 0.f, 0.f);
        if (idx >= 0) vx = *(const float4*)(x + (size_t)idx * 64 + c4);
        _Float16* p = &hA[r * LDH + c4];
        p[0] = (_Float16)vx.x; p[1] = (_Float16)vx.y;
        p[2] = (_Float16)vx.z; p[3] = (_Float16)vx.w;
        int g = sG[r] < 0 ? 0 : sG[r];
        float4 vu = *(const float4*)(u + (size_t)g * 64 + c4);
        _Float16* p2 = &hA[r * LDH + 64 + c4];
        p2[0] = (_Float16)vu.x; p2[1] = (_Float16)vu.y;
        p2[2] = (_Float16)vu.z; p2[3] = (_Float16)vu.w;
    }
    __syncthreads();

    // ---- layers 1 & 2: 128x128, relu, in-place in hA ----
    const int rowg = (wave >> 1) * 64;
    const int colg = (wave & 1) * 64;
    for (int layer = 0; layer < 2; ++layer) {
        const _Float16* wT = layer ? w2T : w1T;
        const float* bias = layer ? b2 : b1;
        floatx4 acc[4][4];
        #pragma unroll
        for (int ct = 0; ct < 4; ++ct) {
            float bv = bias[colg + ct * 16 + l16];
            #pragma unroll
            for (int rt = 0; rt < 4; ++rt) acc[rt][ct] = (floatx4){bv, bv, bv, bv};
        }
        half8 bfr[4][4];
        #pragma unroll
        for (int ks = 0; ks < 4; ++ks)
            #pragma unroll
            for (int ct = 0; ct < 4; ++ct)
                bfr[ks][ct] = *(const half8*)(wT + (colg + ct * 16 + l16) * 128 + ks * 32 + q * 8);
        #pragma unroll
        for (int ks = 0; ks < 4; ++ks) {
            half8 af[4];
            #pragma unroll
            for (int rt = 0; rt < 4; ++rt)
                af[rt] = *(const half8*)(&hA[(rowg + rt * 16 + l16) * LDH + ks * 32 + q * 8]);
            #pragma unroll
            for (int rt = 0; rt < 4; ++rt)
                #pragma unroll
                for (int ct = 0; ct < 4; ++ct)
                    acc[rt][ct] = __builtin_amdgcn_mfma_f32_16x16x32_f16(
                        af[rt], bfr[ks][ct], acc[rt][ct], 0, 0, 0);
        }
        __syncthreads();
        #pragma unroll
        for (int rt = 0; rt < 4; ++rt)
            #pragma unroll
            for (int ct = 0; ct < 4; ++ct)
                #pragma unroll
                for (int j = 0; j < 4; ++j) {
                    float v = acc[rt][ct][j];
                    v = v > 0.f ? v : 0.f;
                    hA[(rowg + rt * 16 + q * 4 + j) * LDH + colg + ct * 16 + l16] = (_Float16)v;
                }
        __syncthreads();
    }

    // ---- layer 3: 128x64 + LN -> hF (fp32) ----
    {
        const int rowg3 = wave * 32;
        floatx4 acc[2][4];
        #pragma unroll
        for (int ct = 0; ct < 4; ++ct) {
            float bv = b3[ct * 16 + l16];
            acc[0][ct] = (floatx4){bv, bv, bv, bv};
            acc[1][ct] = (floatx4){bv, bv, bv, bv};
        }
        half8 bfr[4][4];
        #pragma unroll
        for (int ks = 0; ks < 4; ++ks)
            #pragma unroll
            for (int ct = 0; ct < 4; ++ct)
                bfr[ks][ct] = *(const half8*)(w3T + (ct * 16 + l16) * 128 + ks * 32 + q * 8);
        #pragma unroll
        for (int ks = 0; ks < 4; ++ks) {
            half8 af[2];
            #pragma unroll
            for (int rt = 0; rt < 2; ++rt)
                af[rt] = *(const half8*)(&hA[(rowg3 + rt * 16 + l16) * LDH + ks * 32 + q * 8]);
            #pragma unroll
            for (int rt = 0; rt < 2; ++rt)
                #pragma unroll
                for (int ct = 0; ct < 4; ++ct)
                    acc[rt][ct] = __builtin_amdgcn_mfma_f32_16x16x32_f16(
                        af[rt], bfr[ks][ct], acc[rt][ct], 0, 0, 0);
        }
        __syncthreads();   // all hA fragment reads done before fp32 overwrite
        float gct[4], bct[4];
        #pragma unroll
        for (int ct = 0; ct < 4; ++ct) {
            gct[ct] = lng[ct * 16 + l16];
            bct[ct] = lnb[ct * 16 + l16];
        }
        #pragma unroll
        for (int rt = 0; rt < 2; ++rt)
            #pragma unroll
            for (int j = 0; j < 4; ++j) {
                int rloc = rowg3 + rt * 16 + q * 4 + j;
                float v0 = acc[rt][0][j], v1 = acc[rt][1][j];
                float v2 = acc[rt][2][j], v3 = acc[rt][3][j];
                float s = v0 + v1 + v2 + v3;
                float ss = v0 * v0 + v1 * v1 + v2 * v2 + v3 * v3;
                #pragma unroll
                for (int m = 1; m < 16; m <<= 1) {
                    s += __shfl_xor(s, m, 16);
                    ss += __shfl_xor(ss, m, 16);
                }
                float mean = s * (1.f / 64.f);
                float var = ss * (1.f / 64.f) - mean * mean;
                float rstd = rsqrtf(var + 1e-5f);
                hF[rloc * LDF + 0  + l16] = (v0 - mean) * rstd * gct[0] + bct[0];
                hF[rloc * LDF + 16 + l16] = (v1 - mean) * rstd * gct[1] + bct[1];
                hF[rloc * LDF + 32 + l16] = (v2 - mean) * rstd * gct[2] + bct[2];
                hF[rloc * LDF + 48 + l16] = (v3 - mean) * rstd * gct[3] + bct[3];
            }
    }
    __syncthreads();

    // ---- run-length segment reduction: wave w handles rows [32w,32w+32) ----
    {
        int c = lane;             // column 0..63
        int r0 = wave * 32;
        int curg = -1;
        float s = 0.f;
        for (int r = r0; r < r0 + 32; ++r) {
            int gg = sG[r];       // wave-uniform
            float v = hF[r * LDF + c];
            if (gg != curg) {
                if (curg >= 0) unsafeAtomicAdd(&agg[(size_t)curg * 64 + c], s);
                curg = gg; s = v;
            } else {
                s += v;
            }
        }
        if (curg >= 0) unsafeAtomicAdd(&agg[(size_t)curg * 64 + c], s);
    }
}

// -------- phase 2: per-graph MLP, MFMA, rows = graphs (32 blocks) --------
__global__ __launch_bounds__(256, 2) void graph_kernel(
    const float* __restrict__ aggF, const float* __restrict__ u,
    const _Float16* __restrict__ w4T, const _Float16* __restrict__ w5T,
    const _Float16* __restrict__ w6T,
    const float* __restrict__ b4, const float* __restrict__ b5, const float* __restrict__ b6,
    const float* __restrict__ g2, const float* __restrict__ bb2,
    float* __restrict__ out)
{
    __shared__ __align__(16) _Float16 hA[ROWS * LDH];

    const int tid = threadIdx.x;
    const int rowbase = blockIdx.x * ROWS;
    const int wave = tid >> 6;
    const int lane = tid & 63;
    const int q = lane >> 4;
    const int l16 = lane & 15;

    // stage concat(agg, u) as f16
    for (int i = tid; i < ROWS * 16; i += 256) {
        int r = i >> 4, c4 = (i & 15) << 2;
        size_t row = (size_t)(rowbase + r) * 64 + c4;
        float4 va = *(const float4*)(aggF + row);
        _Float16* p = &hA[r * LDH + c4];
        p[0] = (_Float16)va.x; p[1] = (_Float16)va.y;
        p[2] = (_Float16)va.z; p[3] = (_Float16)va.w;
        float4 vu = *(const float4*)(u + row);
        _Float16* p2 = &hA[r * LDH + 64 + c4];
        p2[0] = (_Float16)vu.x; p2[1] = (_Float16)vu.y;
        p2[2] = (_Float16)vu.z; p2[3] = (_Float16)vu.w;
    }
    __syncthreads();

    const int rowg = (wave >> 1) * 64;
    const int colg = (wave & 1) * 64;
    for (int layer = 0; layer < 2; ++layer) {
        const _Float16* wT = layer ? w5T : w4T;
        const float* bias = layer ? b5 : b4;
        floatx4 acc[4][4];
        #pragma unroll
        for (int ct = 0; ct < 4; ++ct) {
            float bv = bias[colg + ct * 16 + l16];
            #pragma unroll
            for (int rt = 0; rt < 4; ++rt) acc[rt][ct] = (floatx4){bv, bv, bv, bv};
        }
        half8 bfr[4][4];
        #pragma unroll
        for (int ks = 0; ks < 4; ++ks)
            #pragma unroll
            for (int ct = 0; ct < 4; ++ct)
                bfr[ks][ct] = *(const half8*)(wT + (colg + ct * 16 + l16) * 128 + ks * 32 + q * 8);
        #pragma unroll
        for (int ks = 0; ks < 4; ++ks) {
            half8 af[4];
            #pragma unroll
            for (int rt = 0; rt < 4; ++rt)
                af[rt] = *(const half8*)(&hA[(rowg + rt * 16 + l16) * LDH + ks * 32 + q * 8]);
            #pragma unroll
            for (int rt = 0; rt < 4; ++rt)
                #pragma unroll
                for (int ct = 0; ct < 4; ++ct)
                    acc[rt][ct] = __builtin_amdgcn_mfma_f32_16x16x32_f16(
                        af[rt], bfr[ks][ct], acc[rt][ct], 0, 0, 0);
        }
        __syncthreads();
        #pragma unroll
        for (int rt = 0; rt < 4; ++rt)
            #pragma unroll
            for (int ct = 0; ct < 4; ++ct)
                #pragma unroll
                for (int j = 0; j < 4; ++j) {
                    float v = acc[rt][ct][j];
                    v = v > 0.f ? v : 0.f;
                    hA[(rowg + rt * 16 + q * 4 + j) * LDH + colg + ct * 16 + l16] = (_Float16)v;
                }
        __syncthreads();
    }

    // layer 6: 128x64 + LN + residual + store
    {
        const int rowg3 = wave * 32;
        floatx4 acc[2][4];
        #pragma unroll
        for (int ct = 0; ct < 4; ++ct) {
            float bv = b6[ct * 16 + l16];
            acc[0][ct] = (floatx4){bv, bv, bv, bv};
            acc[1][ct] = (floatx4){bv, bv, bv, bv};
        }
        half8 bfr[4][4];
        #pragma unroll
        for (int ks = 0; ks < 4; ++ks)
            #pragma unroll
            for (int ct = 0; ct < 4; ++ct)
                bfr[ks][ct] = *(const half8*)(w6T + (ct * 16 + l16) * 128 + ks * 32 + q * 8);
        #pragma unroll
        for (int ks = 0; ks < 4; ++ks) {
            half8 af[2];
            #pragma unroll
            for (int rt = 0; rt < 2; ++rt)
                af[rt] = *(const half8*)(&hA[(rowg3 + rt * 16 + l16) * LDH + ks * 32 + q * 8]);
            #pragma unroll
            for (int rt = 0; rt < 2; ++rt)
                #pragma unroll
                for (int ct = 0; ct < 4; ++ct)
                    acc[rt][ct] = __builtin_amdgcn_mfma_f32_16x16x32_f16(
                        af[rt], bfr[ks][ct], acc[rt][ct], 0, 0, 0);
        }
        float gct[4], bct[4];
        #pragma unroll
        for (int ct = 0; ct < 4; ++ct) {
            gct[ct] = g2[ct * 16 + l16];
            bct[ct] = bb2[ct * 16 + l16];
        }
        #pragma unroll
        for (int rt = 0; rt < 2; ++rt)
            #pragma unroll
            for (int j = 0; j < 4; ++j) {
                int rloc = rowg3 + rt * 16 + q * 4 + j;
                size_t grow = (size_t)(rowbase + rloc) * 64;
                float v0 = acc[rt][0][j], v1 = acc[rt][1][j];
                float v2 = acc[rt][2][j], v3 = acc[rt][3][j];
                float s = v0 + v1 + v2 + v3;
                float ss = v0 * v0 + v1 * v1 + v2 * v2 + v3 * v3;
                #pragma unroll
                for (int m = 1; m < 16; m <<= 1) {
                    s += __shfl_xor(s, m, 16);
                    ss += __shfl_xor(ss, m, 16);
                }
                float mean = s * (1.f / 64.f);
                float var = ss * (1.f / 64.f) - mean * mean;
                float rstd = rsqrtf(var + 1e-5f);
                out[grow + 0  + l16] = (v0 - mean) * rstd * gct[0] + bct[0] + u[grow + 0  + l16];
                out[grow + 16 + l16] = (v1 - mean) * rstd * gct[1] + bct[1] + u[grow + 16 + l16];
                out[grow + 32 + l16] = (v2 - mean) * rstd * gct[2] + bct[2] + u[grow + 32 + l16];
                out[grow + 48 + l16] = (v3 - mean) * rstd * gct[3] + bct[3] + u[grow + 48 + l16];
            }
    }
}

extern "C" void kernel_launch(void* const* d_in, const int* in_sizes, int n_in,
                              void* d_out, int out_size, void* d_ws, size_t ws_size,
                              hipStream_t stream) {
    const float* x   = (const float*)d_in[0];
    const float* u   = (const float*)d_in[1];
    const int*   bt  = (const int*)d_in[2];
    const float* w1  = (const float*)d_in[3];
    const float* b1  = (const float*)d_in[4];
    const float* w2  = (const float*)d_in[5];
    const float* b2  = (const float*)d_in[6];
    const float* w3  = (const float*)d_in[7];
    const float* b3  = (const float*)d_in[8];
    const float* lng = (const float*)d_in[9];
    const float* lnb = (const float*)d_in[10];
    const float* w4  = (const float*)d_in[11];
    const float* b4  = (const float*)d_in[12];
    const float* w5  = (const float*)d_in[13];
    const float* b5  = (const float*)d_in[14];
    const float* w6  = (const float*)d_in[15];
    const float* b6  = (const float*)d_in[16];
    const float* g2  = (const float*)d_in[17];
    const float* bb2 = (const float*)d_in[18];
    float* out = (float*)d_out;

    char* p = (char*)d_ws;
    // zeroed region: cnt | cursor | agg (contiguous)
    int* cnt        = (int*)p;                 p += 4096 * 4;
    int* cursor     = (int*)p;                 p += 4096 * 4;
    float* agg      = (float*)p;               p += (size_t)NGRAPHS * 64 * 4;
    int* offs       = (int*)p;                 p += 4100 * 4;
    int* sorted     = (int*)p;                 p += NNODES * 4;
    int* sortedG    = (int*)p;                 p += NNODES * 4;
    _Float16* w1T   = (_Float16*)p;            p += 128 * 128 * 2;
    _Float16* w2T   = (_Float16*)p;            p += 128 * 128 * 2;
    _Float16* w3T   = (_Float16*)p;            p += 64 * 128 * 2;
    _Float16* w4T   = (_Float16*)p;            p += 128 * 128 * 2;
    _Float16* w5T   = (_Float16*)p;            p += 128 * 128 * 2;
    _Float16* w6T   = (_Float16*)p;            p += 64 * 128 * 2;

    hipMemsetAsync(cnt, 0, (2 * 4096 + NGRAPHS * 64) * sizeof(float), stream);
    prep_kernel<<<128, 256, 0, stream>>>(w1, w2, w3, w4, w5, w6,
                                         w1T, w2T, w3T, w4T, w5T, w6T);
    hist_kernel<<<(NNODES + 255) / 256, 256, 0, stream>>>(bt, cnt);
    scan_kernel<<<1, 256, 0, stream>>>(cnt, offs);
    scatter_kernel<<<(NNODES + 255) / 256, 256, 0, stream>>>(bt, offs, cursor, sorted, sortedG);
    node_kernel<<<(NNODES + ROWS - 1) / ROWS, 256, 0, stream>>>(
        x, u, sorted, sortedG, w1T, w2T, w3T, b1, b2, b3, lng, lnb, agg);
    graph_kernel<<<NGRAPHS / ROWS, 256, 0, stream>>>(
        agg, u, w4T, w5T, w6T, b4, b5, b6, g2, bb2, out);
}

// Round 6
// 428.445 us; speedup vs baseline: 1.6518x; 1.0010x over previous
//
#include <hip/hip_runtime.h>
#include <hip/hip_bf16.h>
#include <stdint.h>

// GraphNet global block, MI355X. R6 = R5 with the cvt_pkrtz type fixed:
//  - atomic-free counting sort: LDS rank + block-hist -> hierarchical scan ->
//    arithmetic place (replaces ~220us of contended global atomics)
//  - node_kernel: 512 threads, (512,3) => ~24 waves/CU, packed f16 LDS staging
// Phase 2 = small MFMA graph kernel (unchanged from R4).

#define NNODES 500000
#define NGRAPHS 4096
#define ROWS 128
#define LDH 136       // padded f16 row stride (272 B)
#define LDF 66        // padded f32 row stride for LN-output reuse of hA
#define NB 128        // sort blocks (chunk = 4096 nodes, i>>12)

typedef __attribute__((ext_vector_type(8))) _Float16 half8;
typedef __attribute__((ext_vector_type(2))) __fp16 fp16x2;
typedef __attribute__((ext_vector_type(4))) float floatx4;

__device__ inline unsigned pk2(float a, float b) {
    union { fp16x2 h; unsigned u; } c;
    c.h = __builtin_amdgcn_cvt_pkrtz(a, b);
    return c.u;
}

// ------------- prep: transpose all 6 weights to f16 [N][K] -------------
__global__ void prep_kernel(const float* __restrict__ w1, const float* __restrict__ w2,
                            const float* __restrict__ w3,
                            const float* __restrict__ w4, const float* __restrict__ w5,
                            const float* __restrict__ w6,
                            _Float16* __restrict__ w1T, _Float16* __restrict__ w2T,
                            _Float16* __restrict__ w3T,
                            _Float16* __restrict__ w4T, _Float16* __restrict__ w5T,
                            _Float16* __restrict__ w6T) {
    int i = blockIdx.x * 256 + threadIdx.x;
    if (i < 128 * 128) {
        int n = i >> 7, k = i & 127;
        w1T[i] = (_Float16)w1[k * 128 + n];
        w2T[i] = (_Float16)w2[k * 128 + n];
        w4T[i] = (_Float16)w4[k * 128 + n];
        w5T[i] = (_Float16)w5[k * 128 + n];
    }
    if (i < 64 * 128) {
        int n = i >> 7, k = i & 127;
        w3T[i] = (_Float16)w3[k * 64 + n];
        w6T[i] = (_Float16)w6[k * 64 + n];
    }
}

// ------------- sort A: per-block LDS hist + local rank (no global atomics) ---
__global__ __launch_bounds__(1024) void rank_kernel(const int* __restrict__ batch,
                                                    int* __restrict__ lrank,
                                                    unsigned* __restrict__ bhist) {
    __shared__ unsigned lh[NGRAPHS];
    const int t = threadIdx.x, b = blockIdx.x;
    for (int j = t; j < NGRAPHS; j += 1024) lh[j] = 0;
    __syncthreads();
    const int base = b << 12;
    #pragma unroll
    for (int j = 0; j < 4; ++j) {
        int i = base + j * 1024 + t;
        if (i < NNODES) {
            int g = batch[i];
            lrank[i] = atomicAdd(&lh[g], 1u);   // LDS atomic
        }
    }
    __syncthreads();
    for (int j = t; j < NGRAPHS; j += 1024) bhist[(size_t)j * NB + b] = lh[j];
}

// ------------- sort B1: scan 1024-chunks of bhist (graph-major) -------------
__global__ void scan1_kernel(unsigned* __restrict__ a, unsigned* __restrict__ ctot) {
    __shared__ unsigned ss[256];
    const int t = threadIdx.x, c = blockIdx.x;
    uint4 v = ((uint4*)a)[c * 256 + t];
    unsigned s = v.x + v.y + v.z + v.w;
    ss[t] = s;
    __syncthreads();
    for (int d = 1; d < 256; d <<= 1) {
        unsigned w = (t >= d) ? ss[t - d] : 0;
        __syncthreads();
        ss[t] += w;
        __syncthreads();
    }
    unsigned excl = ss[t] - s;
    uint4 o;
    o.x = excl; o.y = excl + v.x; o.z = o.y + v.y; o.w = o.z + v.z;
    ((uint4*)a)[c * 256 + t] = o;
    if (t == 255) ctot[c] = ss[255];
}

// ------------- sort B2: scan the 512 chunk totals -------------
__global__ void scan2_kernel(const unsigned* __restrict__ ctot, unsigned* __restrict__ cbase) {
    __shared__ unsigned ss[256];
    const int t = threadIdx.x;
    unsigned a = ctot[2 * t], b = ctot[2 * t + 1];
    unsigned s = a + b;
    ss[t] = s;
    __syncthreads();
    for (int d = 1; d < 256; d <<= 1) {
        unsigned w = (t >= d) ? ss[t - d] : 0;
        __syncthreads();
        ss[t] += w;
        __syncthreads();
    }
    unsigned excl = ss[t] - s;
    cbase[2 * t] = excl;
    cbase[2 * t + 1] = excl + a;
}

// ------------- sort C: arithmetic placement (no atomics) -------------
__global__ void place_kernel(const int* __restrict__ batch, const int* __restrict__ lrank,
                             const unsigned* __restrict__ partial,
                             const unsigned* __restrict__ cbase,
                             int* __restrict__ sorted, int* __restrict__ sortedG) {
    int i = blockIdx.x * 256 + threadIdx.x;
    if (i < NNODES) {
        int g = batch[i];
        unsigned idx = (unsigned)g * NB + (unsigned)(i >> 12);
        unsigned p = partial[idx] + cbase[idx >> 10] + (unsigned)lrank[i];
        sorted[p] = i;
        sortedG[p] = g;
    }
}

// -------- phase 1: flat-tiled node MLP + LN + segment-reduce, 512 threads ----
__global__ __launch_bounds__(512, 3) void node_kernel(
    const float* __restrict__ x, const float* __restrict__ u,
    const int* __restrict__ sorted, const int* __restrict__ sortedG,
    const _Float16* __restrict__ w1T, const _Float16* __restrict__ w2T,
    const _Float16* __restrict__ w3T,
    const float* __restrict__ b1, const float* __restrict__ b2, const float* __restrict__ b3,
    const float* __restrict__ lng, const float* __restrict__ lnb,
    float* __restrict__ agg)
{
    __shared__ __align__(16) _Float16 hA[ROWS * LDH];   // 34.8 KB, reused fp32
    __shared__ int sIdx[ROWS];
    __shared__ int sG[ROWS];

    float* hF = (float*)hA;

    const int tid = threadIdx.x;
    const int rowbase = blockIdx.x * ROWS;
    const int wave = tid >> 6;      // 0..7
    const int lane = tid & 63;
    const int q = lane >> 4;
    const int l16 = lane & 15;

    if (tid < ROWS) {
        int gr = rowbase + tid;
        if (gr < NNODES) { sIdx[tid] = sorted[gr]; sG[tid] = sortedG[gr]; }
        else             { sIdx[tid] = -1;         sG[tid] = -1; }
    }
    __syncthreads();

    // stage h0 = concat(x[idx], u[g]) as f16 (packed b64 writes)
    for (int i = tid; i < ROWS * 16; i += 512) {
        int r = i >> 4, c4 = (i & 15) << 2;
        int idx = sIdx[r];
        float4 vx = make_float4(0.f, 0.f, 0.f, 0.f);
        if (idx >= 0) vx = *(const float4*)(x + (size_t)idx * 64 + c4);
        uint2 px = make_uint2(pk2(vx.x, vx.y), pk2(vx.z, vx.w));
        *(uint2*)(&hA[r * LDH + c4]) = px;
        int g = sG[r] < 0 ? 0 : sG[r];
        float4 vu = *(const float4*)(u + (size_t)g * 64 + c4);
        uint2 pu = make_uint2(pk2(vu.x, vu.y), pk2(vu.z, vu.w));
        *(uint2*)(&hA[r * LDH + 64 + c4]) = pu;
    }
    __syncthreads();

    // ---- layers 1 & 2: 128x128, relu, in-place; wave tile = 32 rows x 64 cols
    const int rowg = (wave >> 1) * 32;
    const int colg = (wave & 1) * 64;
    for (int layer = 0; layer < 2; ++layer) {
        const _Float16* wT = layer ? w2T : w1T;
        const float* bias = layer ? b2 : b1;
        floatx4 acc[2][4];
        #pragma unroll
        for (int ct = 0; ct < 4; ++ct) {
            float bv = bias[colg + ct * 16 + l16];
            acc[0][ct] = (floatx4){bv, bv, bv, bv};
            acc[1][ct] = (floatx4){bv, bv, bv, bv};
        }
        half8 bfr[4][4];
        #pragma unroll
        for (int ks = 0; ks < 4; ++ks)
            #pragma unroll
            for (int ct = 0; ct < 4; ++ct)
                bfr[ks][ct] = *(const half8*)(wT + (colg + ct * 16 + l16) * 128 + ks * 32 + q * 8);
        #pragma unroll
        for (int ks = 0; ks < 4; ++ks) {
            half8 af[2];
            #pragma unroll
            for (int rt = 0; rt < 2; ++rt)
                af[rt] = *(const half8*)(&hA[(rowg + rt * 16 + l16) * LDH + ks * 32 + q * 8]);
            #pragma unroll
            for (int rt = 0; rt < 2; ++rt)
                #pragma unroll
                for (int ct = 0; ct < 4; ++ct)
                    acc[rt][ct] = __builtin_amdgcn_mfma_f32_16x16x32_f16(
                        af[rt], bfr[ks][ct], acc[rt][ct], 0, 0, 0);
        }
        __syncthreads();
        #pragma unroll
        for (int rt = 0; rt < 2; ++rt)
            #pragma unroll
            for (int ct = 0; ct < 4; ++ct)
                #pragma unroll
                for (int j = 0; j < 4; ++j) {
                    float v = acc[rt][ct][j];
                    v = v > 0.f ? v : 0.f;
                    hA[(rowg + rt * 16 + q * 4 + j) * LDH + colg + ct * 16 + l16] = (_Float16)v;
                }
        __syncthreads();
    }

    // ---- layer 3: 128x64 + LN -> hF (fp32); wave handles 16 rows ----
    {
        const int rowg3 = wave * 16;
        floatx4 acc[4];
        #pragma unroll
        for (int ct = 0; ct < 4; ++ct) {
            float bv = b3[ct * 16 + l16];
            acc[ct] = (floatx4){bv, bv, bv, bv};
        }
        half8 bfr[4][4];
        #pragma unroll
        for (int ks = 0; ks < 4; ++ks)
            #pragma unroll
            for (int ct = 0; ct < 4; ++ct)
                bfr[ks][ct] = *(const half8*)(w3T + (ct * 16 + l16) * 128 + ks * 32 + q * 8);
        #pragma unroll
        for (int ks = 0; ks < 4; ++ks) {
            half8 af = *(const half8*)(&hA[(rowg3 + l16) * LDH + ks * 32 + q * 8]);
            #pragma unroll
            for (int ct = 0; ct < 4; ++ct)
                acc[ct] = __builtin_amdgcn_mfma_f32_16x16x32_f16(af, bfr[ks][ct], acc[ct], 0, 0, 0);
        }
        __syncthreads();   // all hA f16 reads done before fp32 overwrite
        float gct[4], bct[4];
        #pragma unroll
        for (int ct = 0; ct < 4; ++ct) {
            gct[ct] = lng[ct * 16 + l16];
            bct[ct] = lnb[ct * 16 + l16];
        }
        #pragma unroll
        for (int j = 0; j < 4; ++j) {
            int rloc = rowg3 + q * 4 + j;
            float v0 = acc[0][j], v1 = acc[1][j];
            float v2 = acc[2][j], v3 = acc[3][j];
            float s = v0 + v1 + v2 + v3;
            float ss = v0 * v0 + v1 * v1 + v2 * v2 + v3 * v3;
            #pragma unroll
            for (int m = 1; m < 16; m <<= 1) {
                s += __shfl_xor(s, m, 16);
                ss += __shfl_xor(ss, m, 16);
            }
            float mean = s * (1.f / 64.f);
            float var = ss * (1.f / 64.f) - mean * mean;
            float rstd = rsqrtf(var + 1e-5f);
            hF[rloc * LDF + 0  + l16] = (v0 - mean) * rstd * gct[0] + bct[0];
            hF[rloc * LDF + 16 + l16] = (v1 - mean) * rstd * gct[1] + bct[1];
            hF[rloc * LDF + 32 + l16] = (v2 - mean) * rstd * gct[2] + bct[2];
            hF[rloc * LDF + 48 + l16] = (v3 - mean) * rstd * gct[3] + bct[3];
        }
    }
    __syncthreads();

    // ---- run-length segment reduction: waves 0..3, rows [32w, 32w+32) ----
    if (wave < 4) {
        int c = lane;
        int r0 = wave * 32;
        int curg = -1;
        float s = 0.f;
        for (int r = r0; r < r0 + 32; ++r) {
            int gg = sG[r];       // wave-uniform
            float v = hF[r * LDF + c];
            if (gg != curg) {
                if (curg >= 0) unsafeAtomicAdd(&agg[(size_t)curg * 64 + c], s);
                curg = gg; s = v;
            } else {
                s += v;
            }
        }
        if (curg >= 0) unsafeAtomicAdd(&agg[(size_t)curg * 64 + c], s);
    }
}

// -------- phase 2: per-graph MLP, MFMA, rows = graphs (32 blocks) --------
__global__ __launch_bounds__(256, 2) void graph_kernel(
    const float* __restrict__ aggF, const float* __restrict__ u,
    const _Float16* __restrict__ w4T, const _Float16* __restrict__ w5T,
    const _Float16* __restrict__ w6T,
    const float* __restrict__ b4, const float* __restrict__ b5, const float* __restrict__ b6,
    const float* __restrict__ g2, const float* __restrict__ bb2,
    float* __restrict__ out)
{
    __shared__ __align__(16) _Float16 hA[ROWS * LDH];

    const int tid = threadIdx.x;
    const int rowbase = blockIdx.x * ROWS;
    const int wave = tid >> 6;
    const int lane = tid & 63;
    const int q = lane >> 4;
    const int l16 = lane & 15;

    for (int i = tid; i < ROWS * 16; i += 256) {
        int r = i >> 4, c4 = (i & 15) << 2;
        size_t row = (size_t)(rowbase + r) * 64 + c4;
        float4 va = *(const float4*)(aggF + row);
        uint2 pa = make_uint2(pk2(va.x, va.y), pk2(va.z, va.w));
        *(uint2*)(&hA[r * LDH + c4]) = pa;
        float4 vu = *(const float4*)(u + row);
        uint2 pu = make_uint2(pk2(vu.x, vu.y), pk2(vu.z, vu.w));
        *(uint2*)(&hA[r * LDH + 64 + c4]) = pu;
    }
    __syncthreads();

    const int rowg = (wave >> 1) * 64;
    const int colg = (wave & 1) * 64;
    for (int layer = 0; layer < 2; ++layer) {
        const _Float16* wT = layer ? w5T : w4T;
        const float* bias = layer ? b5 : b4;
        floatx4 acc[4][4];
        #pragma unroll
        for (int ct = 0; ct < 4; ++ct) {
            float bv = bias[colg + ct * 16 + l16];
            #pragma unroll
            for (int rt = 0; rt < 4; ++rt) acc[rt][ct] = (floatx4){bv, bv, bv, bv};
        }
        half8 bfr[4][4];
        #pragma unroll
        for (int ks = 0; ks < 4; ++ks)
            #pragma unroll
            for (int ct = 0; ct < 4; ++ct)
                bfr[ks][ct] = *(const half8*)(wT + (colg + ct * 16 + l16) * 128 + ks * 32 + q * 8);
        #pragma unroll
        for (int ks = 0; ks < 4; ++ks) {
            half8 af[4];
            #pragma unroll
            for (int rt = 0; rt < 4; ++rt)
                af[rt] = *(const half8*)(&hA[(rowg + rt * 16 + l16) * LDH + ks * 32 + q * 8]);
            #pragma unroll
            for (int rt = 0; rt < 4; ++rt)
                #pragma unroll
                for (int ct = 0; ct < 4; ++ct)
                    acc[rt][ct] = __builtin_amdgcn_mfma_f32_16x16x32_f16(
                        af[rt], bfr[ks][ct], acc[rt][ct], 0, 0, 0);
        }
        __syncthreads();
        #pragma unroll
        for (int rt = 0; rt < 4; ++rt)
            #pragma unroll
            for (int ct = 0; ct < 4; ++ct)
                #pragma unroll
                for (int j = 0; j < 4; ++j) {
                    float v = acc[rt][ct][j];
                    v = v > 0.f ? v : 0.f;
                    hA[(rowg + rt * 16 + q * 4 + j) * LDH + colg + ct * 16 + l16] = (_Float16)v;
                }
        __syncthreads();
    }

    {
        const int rowg3 = wave * 32;
        floatx4 acc[2][4];
        #pragma unroll
        for (int ct = 0; ct < 4; ++ct) {
            float bv = b6[ct * 16 + l16];
            acc[0][ct] = (floatx4){bv, bv, bv, bv};
            acc[1][ct] = (floatx4){bv, bv, bv, bv};
        }
        half8 bfr[4][4];
        #pragma unroll
        for (int ks = 0; ks < 4; ++ks)
            #pragma unroll
            for (int ct = 0; ct < 4; ++ct)
                bfr[ks][ct] = *(const half8*)(w6T + (ct * 16 + l16) * 128 + ks * 32 + q * 8);
        #pragma unroll
        for (int ks = 0; ks < 4; ++ks) {
            half8 af[2];
            #pragma unroll
            for (int rt = 0; rt < 2; ++rt)
                af[rt] = *(const half8*)(&hA[(rowg3 + rt * 16 + l16) * LDH + ks * 32 + q * 8]);
            #pragma unroll
            for (int rt = 0; rt < 2; ++rt)
                #pragma unroll
                for (int ct = 0; ct < 4; ++ct)
                    acc[rt][ct] = __builtin_amdgcn_mfma_f32_16x16x32_f16(
                        af[rt], bfr[ks][ct], acc[rt][ct], 0, 0, 0);
        }
        float gct[4], bct[4];
        #pragma unroll
        for (int ct = 0; ct < 4; ++ct) {
            gct[ct] = g2[ct * 16 + l16];
            bct[ct] = bb2[ct * 16 + l16];
        }
        #pragma unroll
        for (int rt = 0; rt < 2; ++rt)
            #pragma unroll
            for (int j = 0; j < 4; ++j) {
                int rloc = rowg3 + rt * 16 + q * 4 + j;
                size_t grow = (size_t)(rowbase + rloc) * 64;
                float v0 = acc[rt][0][j], v1 = acc[rt][1][j];
                float v2 = acc[rt][2][j], v3 = acc[rt][3][j];
                float s = v0 + v1 + v2 + v3;
                float ss = v0 * v0 + v1 * v1 + v2 * v2 + v3 * v3;
                #pragma unroll
                for (int m = 1; m < 16; m <<= 1) {
                    s += __shfl_xor(s, m, 16);
                    ss += __shfl_xor(ss, m, 16);
                }
                float mean = s * (1.f / 64.f);
                float var = ss * (1.f / 64.f) - mean * mean;
                float rstd = rsqrtf(var + 1e-5f);
                out[grow + 0  + l16] = (v0 - mean) * rstd * gct[0] + bct[0] + u[grow + 0  + l16];
                out[grow + 16 + l16] = (v1 - mean) * rstd * gct[1] + bct[1] + u[grow + 16 + l16];
                out[grow + 32 + l16] = (v2 - mean) * rstd * gct[2] + bct[2] + u[grow + 32 + l16];
                out[grow + 48 + l16] = (v3 - mean) * rstd * gct[3] + bct[3] + u[grow + 48 + l16];
            }
    }
}

extern "C" void kernel_launch(void* const* d_in, const int* in_sizes, int n_in,
                              void* d_out, int out_size, void* d_ws, size_t ws_size,
                              hipStream_t stream) {
    const float* x   = (const float*)d_in[0];
    const float* u   = (const float*)d_in[1];
    const int*   bt  = (const int*)d_in[2];
    const float* w1  = (const float*)d_in[3];
    const float* b1  = (const float*)d_in[4];
    const float* w2  = (const float*)d_in[5];
    const float* b2  = (const float*)d_in[6];
    const float* w3  = (const float*)d_in[7];
    const float* b3  = (const float*)d_in[8];
    const float* lng = (const float*)d_in[9];
    const float* lnb = (const float*)d_in[10];
    const float* w4  = (const float*)d_in[11];
    const float* b4  = (const float*)d_in[12];
    const float* w5  = (const float*)d_in[13];
    const float* b5  = (const float*)d_in[14];
    const float* w6  = (const float*)d_in[15];
    const float* b6  = (const float*)d_in[16];
    const float* g2  = (const float*)d_in[17];
    const float* bb2 = (const float*)d_in[18];
    float* out = (float*)d_out;

    char* p = (char*)d_ws;
    float* agg       = (float*)p;              p += (size_t)NGRAPHS * 64 * 4;
    int* lrank       = (int*)p;                p += (size_t)NNODES * 4;
    unsigned* bhist  = (unsigned*)p;           p += (size_t)NGRAPHS * NB * 4;   // 2 MB
    unsigned* ctot   = (unsigned*)p;           p += 512 * 4;
    unsigned* cbase  = (unsigned*)p;           p += 512 * 4;
    int* sorted      = (int*)p;                p += (size_t)NNODES * 4;
    int* sortedG     = (int*)p;                p += (size_t)NNODES * 4;
    _Float16* w1T    = (_Float16*)p;           p += 128 * 128 * 2;
    _Float16* w2T    = (_Float16*)p;           p += 128 * 128 * 2;
    _Float16* w3T    = (_Float16*)p;           p += 64 * 128 * 2;
    _Float16* w4T    = (_Float16*)p;           p += 128 * 128 * 2;
    _Float16* w5T    = (_Float16*)p;           p += 128 * 128 * 2;
    _Float16* w6T    = (_Float16*)p;           p += 64 * 128 * 2;

    (void)hipMemsetAsync(agg, 0, (size_t)NGRAPHS * 64 * sizeof(float), stream);
    prep_kernel<<<128, 256, 0, stream>>>(w1, w2, w3, w4, w5, w6,
                                         w1T, w2T, w3T, w4T, w5T, w6T);
    rank_kernel<<<NB, 1024, 0, stream>>>(bt, lrank, bhist);
    scan1_kernel<<<(NGRAPHS * NB) / 1024, 256, 0, stream>>>(bhist, ctot);
    scan2_kernel<<<1, 256, 0, stream>>>(ctot, cbase);
    place_kernel<<<(NNODES + 255) / 256, 256, 0, stream>>>(bt, lrank, bhist, cbase,
                                                           sorted, sortedG);
    node_kernel<<<(NNODES + ROWS - 1) / ROWS, 512, 0, stream>>>(
        x, u, sorted, sortedG, w1T, w2T, w3T, b1, b2, b3, lng, lnb, agg);
    graph_kernel<<<NGRAPHS / ROWS, 256, 0, stream>>>(
        agg, u, w4T, w5T, w6T, b4, b5, b6, g2, bb2, out);
}